// Round 2
// baseline (337.945 us; speedup 1.0000x reference)
//
#include <hip/hip_runtime.h>

// ---------------------------------------------------------------------------
// CapsuleSequenceToGraph: 4 modalities, B=64, T in {128,512,256,256},
// MULT_D=64, n_vertex=32, d_cap=16, routing=3.  Inputs/outputs: fp32.
//
// Key identity: b_k[b,t,n] = <Vcum_k[b,n,:], pri[b,t,n,:]> with Vcum_k = sum v_i
// (b_0 = 0 and the update is linear in pri). Each routing iteration is ONE
// streaming pass over pri with only Vcum (0.5 MB fp32) carried between passes.
// rc_0 = softmax(0) falls out of Vcum = 0 automatically.
//
// ws layout:
//   [0, 75497472)            pri, bf16, [mod][b][t][n*16+d]
//   [75497472, +524288)      S,    fp32, [mod][b][n*16+d]  (4*64*512)
//   [76021760, +524288)      Vcum, fp32, same layout
// ---------------------------------------------------------------------------

#define PRI_BYTES 75497472ull
#define S_ELEMS 131072

static __device__ __forceinline__ unsigned short f2bf(float f) {
  union { float f; unsigned int i; } v;
  v.f = f;
  unsigned int x = v.i;
  return (unsigned short)((x + 0x7fffu + ((x >> 16) & 1u)) >> 16);  // RNE
}

// ---------------------------------------------------------------------------
// Phase 1: pri[b,t,n,d] = sum_j x[b,t,j] * W[t,n,j,d]
// One block per t (1152 blocks, all modalities). Per block a
// [64 x 64] @ [64 x 512] GEMM: x row-tile in LDS, W in 4 chunks of
// 128 output-cols (8 n's) in LDS. Thread (ty,tx) computes 4 b x 8 nd.
// ---------------------------------------------------------------------------
__global__ __launch_bounds__(256) void pri_kernel(
    const float* __restrict__ x0, const float* __restrict__ x1,
    const float* __restrict__ x2, const float* __restrict__ x3,
    const float* __restrict__ w0, const float* __restrict__ w1,
    const float* __restrict__ w2, const float* __restrict__ w3,
    unsigned short* __restrict__ priAll) {
  __shared__ float xs[64][65];    // +1 pad: conflict-free reads
  __shared__ float wl[64][132];   // 132 % 32 = 4: breaks j-stride conflicts

  int blk = blockIdx.x;
  const float* x;
  const float* W;
  unsigned short* pri;
  int T, t;
  if (blk < 128)      { x = x0; W = w0; pri = priAll;               T = 128; t = blk; }
  else if (blk < 640) { x = x1; W = w1; pri = priAll + 4194304ull;  T = 512; t = blk - 128; }
  else if (blk < 896) { x = x2; W = w2; pri = priAll + 20971520ull; T = 256; t = blk - 640; }
  else                { x = x3; W = w3; pri = priAll + 29360128ull; T = 256; t = blk - 896; }

  int tid = threadIdx.x;
  {  // stage x[:, t, :] -> xs (64 rows x 64 cols), float4 loads
    int b = tid >> 2;
    int seg = (tid & 3) << 4;
    const float4* p = reinterpret_cast<const float4*>(x + ((size_t)b * T + t) * 64 + seg);
#pragma unroll
    for (int k = 0; k < 4; ++k) {
      float4 v = p[k];
      xs[b][seg + 4 * k + 0] = v.x;
      xs[b][seg + 4 * k + 1] = v.y;
      xs[b][seg + 4 * k + 2] = v.z;
      xs[b][seg + 4 * k + 3] = v.w;
    }
  }

  int ty = tid >> 4, tx = tid & 15;
  const float* Wt = W + (size_t)t * (32 * 64 * 16);

  for (int c = 0; c < 4; ++c) {
    __syncthreads();
    // stage W[t, c*8 .. c*8+7, :, :] transposed to wl[j][nl*16+d]
#pragma unroll
    for (int r = 0; r < 2; ++r) {
      int q = (tid << 1) | r;  // 0..511 = (nl, j)
      int nl = q >> 6, j = q & 63;
      const float4* p = reinterpret_cast<const float4*>(
          Wt + (((size_t)(c * 8 + nl)) * 64 + j) * 16);
      int col = nl << 4;
#pragma unroll
      for (int k = 0; k < 4; ++k) {
        float4 v = p[k];
        wl[j][col + 4 * k + 0] = v.x;
        wl[j][col + 4 * k + 1] = v.y;
        wl[j][col + 4 * k + 2] = v.z;
        wl[j][col + 4 * k + 3] = v.w;
      }
    }
    __syncthreads();

    float acc0[4][4], acc1[4][4];
#pragma unroll
    for (int bi = 0; bi < 4; ++bi)
#pragma unroll
      for (int i = 0; i < 4; ++i) { acc0[bi][i] = 0.f; acc1[bi][i] = 0.f; }

    for (int j = 0; j < 64; ++j) {
      float wa[4], wb[4];
#pragma unroll
      for (int i = 0; i < 4; ++i) {
        wa[i] = wl[j][(tx << 2) + i];
        wb[i] = wl[j][64 + (tx << 2) + i];
      }
#pragma unroll
      for (int bi = 0; bi < 4; ++bi) {
        float xv = xs[ty + (bi << 4)][j];
#pragma unroll
        for (int i = 0; i < 4; ++i) {
          acc0[bi][i] += xv * wa[i];
          acc1[bi][i] += xv * wb[i];
        }
      }
    }

#pragma unroll
    for (int bi = 0; bi < 4; ++bi) {
      int b = ty + (bi << 4);
      size_t o = ((size_t)b * T + t) * 512 + (c << 7) + (tx << 2);
#pragma unroll
      for (int i = 0; i < 4; ++i) {
        pri[o + i] = f2bf(acc0[bi][i]);
        pri[o + 64 + i] = f2bf(acc1[bi][i]);
      }
    }
  }
}

// ---------------------------------------------------------------------------
// Routing pass: for each (b,t): logits[n] = <Vcum[b,n,:], pri[b,t,n,:]>,
// rc = softmax_n(logits), S[b,n,d] += rc[n]*pri[b,t,n,d].
// Block = (b, 128-t chunk). 8 groups of 32 lanes; lane owns one n.
// 576 blocks: per b -> 1 text + 4 audio + 2 video + 2 frames chunks.
// ---------------------------------------------------------------------------
__global__ __launch_bounds__(256) void pass_kernel(
    const unsigned short* __restrict__ priAll, const float* __restrict__ Vcum,
    float* __restrict__ S) {
  int bb = blockIdx.x / 9;
  int w = blockIdx.x % 9;
  int mod, chunk, T;
  size_t poff;
  if (w == 0)     { mod = 0; chunk = 0;     T = 128; poff = 0; }
  else if (w < 5) { mod = 1; chunk = w - 1; T = 512; poff = 4194304ull; }
  else if (w < 7) { mod = 2; chunk = w - 5; T = 256; poff = 20971520ull; }
  else            { mod = 3; chunk = w - 7; T = 256; poff = 29360128ull; }

  int tid = threadIdx.x;
  int lane = tid & 31;   // n index
  int g = tid >> 5;      // group 0..7

  __shared__ float Sl[512];
  Sl[tid] = 0.f;
  Sl[tid + 256] = 0.f;

  float Vc[16];
  {
    const float* vp = Vcum + (size_t)mod * 32768 + (size_t)bb * 512 + lane * 16;
#pragma unroll
    for (int d = 0; d < 16; ++d) Vc[d] = vp[d];
  }
  __syncthreads();

  float acc[16];
#pragma unroll
  for (int d = 0; d < 16; ++d) acc[d] = 0.f;

  const unsigned short* pb = priAll + poff + (size_t)bb * T * 512;
  int t0 = chunk << 7;
  for (int t = t0 + g; t < t0 + 128; t += 8) {
    const uint4* q = reinterpret_cast<const uint4*>(pb + (size_t)t * 512 + lane * 16);
    uint4 a0 = q[0], a1 = q[1];
    float p[16];
    {
      unsigned int wds[8] = {a0.x, a0.y, a0.z, a0.w, a1.x, a1.y, a1.z, a1.w};
#pragma unroll
      for (int k = 0; k < 8; ++k) {
        union { unsigned int i; float f; } lo, hi;
        lo.i = wds[k] << 16;
        hi.i = wds[k] & 0xffff0000u;
        p[2 * k] = lo.f;
        p[2 * k + 1] = hi.f;
      }
    }
    float logit = 0.f;
#pragma unroll
    for (int d = 0; d < 16; ++d) logit += p[d] * Vc[d];
    // softmax over the 32 lanes (n axis)
    float m = logit;
#pragma unroll
    for (int o = 16; o >= 1; o >>= 1) m = fmaxf(m, __shfl_xor(m, o, 32));
    float e = __expf(logit - m);
    float s = e;
#pragma unroll
    for (int o = 16; o >= 1; o >>= 1) s += __shfl_xor(s, o, 32);
    float rc = e / s;
#pragma unroll
    for (int d = 0; d < 16; ++d) acc[d] += rc * p[d];
  }

#pragma unroll
  for (int d = 0; d < 16; ++d) atomicAdd(&Sl[lane * 16 + d], acc[d]);
  __syncthreads();

  float* sg = S + (size_t)mod * 32768 + (size_t)bb * 512;
  atomicAdd(&sg[tid], Sl[tid]);
  atomicAdd(&sg[tid + 256], Sl[tid + 256]);
}

// Vcum += tanh(S); S = 0   (between passes)
__global__ __launch_bounds__(256) void v_kernel(float* __restrict__ S,
                                                float* __restrict__ Vcum) {
  int i = blockIdx.x * 256 + threadIdx.x;
  float s = S[i];
  Vcum[i] += tanhf(s);
  S[i] = 0.f;
}

// out = tanh(S), fp32  (final)
__global__ __launch_bounds__(256) void out_kernel(const float* __restrict__ S,
                                                  float* __restrict__ out) {
  int i = blockIdx.x * 256 + threadIdx.x;
  out[i] = tanhf(S[i]);
}

extern "C" void kernel_launch(void* const* d_in, const int* in_sizes, int n_in,
                              void* d_out, int out_size, void* d_ws, size_t ws_size,
                              hipStream_t stream) {
  const float* x0 = (const float*)d_in[0];
  const float* x1 = (const float*)d_in[1];
  const float* x2 = (const float*)d_in[2];
  const float* x3 = (const float*)d_in[3];
  const float* w0 = (const float*)d_in[4];
  const float* w1 = (const float*)d_in[5];
  const float* w2 = (const float*)d_in[6];
  const float* w3 = (const float*)d_in[7];

  unsigned short* pri = (unsigned short*)d_ws;
  float* S = (float*)((char*)d_ws + PRI_BYTES);
  float* Vcum = S + S_ELEMS;

  // zero S and Vcum (contiguous 1 MB); ws is re-poisoned before every launch
  hipMemsetAsync(S, 0, 2 * S_ELEMS * sizeof(float), stream);

  pri_kernel<<<1152, 256, 0, stream>>>(x0, x1, x2, x3, w0, w1, w2, w3, pri);

  for (int p = 0; p < 4; ++p) {
    pass_kernel<<<576, 256, 0, stream>>>(pri, Vcum, S);
    if (p < 3) v_kernel<<<512, 256, 0, stream>>>(S, Vcum);
  }
  out_kernel<<<512, 256, 0, stream>>>(S, (float*)d_out);
}

// Round 3
// 317.243 us; speedup vs baseline: 1.0653x; 1.0653x over previous
//
#include <hip/hip_runtime.h>

// ---------------------------------------------------------------------------
// CapsuleSequenceToGraph, fp32 in/out. B=64, T={128,512,256,256}, n=32, d=16.
// Identity: b_k[b,t,n] = <Vcum_k[b,n,:], pri[b,t,n,:]>, Vcum_k = sum_{i<k} v_i.
//
// pri workspace layout (bf16/ushort), per mod: [t][mt=4][bl=16][n=32][d=16]
//   (mt*16+bl = b). This is the MFMA C-layout-friendly order AND gives the
//   routing passes perfectly coalesced 2KB/wave reads.
// ws (bytes):
//   [0, 75497472)              pri bf16
//   [75497472, +9437184)       P   fp32 partial S, 72 slices x 32768
//   [84934656, +524288)        Vcum fp32 [mod][b][n*16+d]
// ---------------------------------------------------------------------------

typedef __attribute__((ext_vector_type(8))) short short8;
typedef __attribute__((ext_vector_type(4))) float floatx4;

#define PRI_BYTES 75497472ull
#define P_FLOATS 2359296ull

static __device__ __forceinline__ unsigned short f2bf(float f) {
  union { float f; unsigned int i; } v;
  v.f = f;
  unsigned int x = v.i;
  return (unsigned short)((x + 0x7fffu + ((x >> 16) & 1u)) >> 16);  // RNE
}

// ---------------------------------------------------------------------------
// pri[b,t,n,d] = sum_j x[b,t,j] * W[t,n,j,d], via bf16 MFMA 16x16x32.
// One block per t. M=64(b) x N=512(nd) x K=64(j). Wave mt owns 16 b-rows.
// A-frag from global (x rows, cvt bf16); B-frag from LDS wb[nd][j] bf16.
// Blocks 0..255 also zero Vcum.
// ---------------------------------------------------------------------------
__global__ __launch_bounds__(256) void pri_kernel(
    const float* __restrict__ x0, const float* __restrict__ x1,
    const float* __restrict__ x2, const float* __restrict__ x3,
    const float* __restrict__ w0, const float* __restrict__ w1,
    const float* __restrict__ w2, const float* __restrict__ w3,
    unsigned short* __restrict__ priAll, float* __restrict__ Vcum) {
  __shared__ unsigned short wb[512 * 72];  // [nd][j], pitch 72 (2-way max)

  int blk = blockIdx.x;
  int tid = threadIdx.x;

  if (blk < 256) {  // zero Vcum (read by pass 0 after this kernel completes)
    int i = blk * 512 + tid * 2;
    Vcum[i] = 0.f;
    Vcum[i + 1] = 0.f;
  }

  const float* x;
  const float* W;
  unsigned short* priT;
  int T, t;
  if (blk < 128)      { x = x0; W = w0; priT = priAll;               T = 128; t = blk; }
  else if (blk < 640) { x = x1; W = w1; priT = priAll + 4194304ull;  T = 512; t = blk - 128; }
  else if (blk < 896) { x = x2; W = w2; priT = priAll + 20971520ull; T = 256; t = blk - 640; }
  else                { x = x3; W = w3; priT = priAll + 29360128ull; T = 256; t = blk - 896; }
  priT += (size_t)t * 32768;

  // ---- stage W[t] (32768 fp32) -> wb[nd][j] bf16, pitch 72 ----
  {
    const floatx4* Wf4 = (const floatx4*)(W + (size_t)t * 32768);
    unsigned int* wb32 = (unsigned int*)wb;  // pitch 36 dwords
#pragma unroll
    for (int it = 0; it < 16; ++it) {
      int idx = it * 256 + tid;            // 0..4095: float4-pairs
      int n = idx >> 7, jp = (idx >> 2) & 31, dq = idx & 3;
      floatx4 fa = Wf4[n * 256 + (2 * jp) * 4 + dq];       // W[n][2jp][4dq..+4]
      floatx4 fb = Wf4[n * 256 + (2 * jp + 1) * 4 + dq];   // W[n][2jp+1][..]
      int rbase = n * 16 + dq * 4;
#pragma unroll
      for (int k = 0; k < 4; ++k) {
        unsigned int dw = (unsigned int)f2bf(fa[k]) | ((unsigned int)f2bf(fb[k]) << 16);
        wb32[(rbase + k) * 36 + jp] = dw;  // row=nd, dword col=jp (j=2jp,2jp+1)
      }
    }
  }

  // ---- A fragments: x[b=mt*16+m][k=s*32+q*8+i], cvt to bf16 ----
  int lane = tid & 63, mt = tid >> 6;
  int m = lane & 15, q = lane >> 4;
  short8 afrag[2];
  {
    const float* xrow = x + ((size_t)(mt * 16 + m) * T + t) * 64;
#pragma unroll
    for (int s = 0; s < 2; ++s) {
      const floatx4* xp = (const floatx4*)(xrow + s * 32 + q * 8);
      floatx4 u0 = xp[0], u1 = xp[1];
      afrag[s][0] = (short)f2bf(u0[0]); afrag[s][1] = (short)f2bf(u0[1]);
      afrag[s][2] = (short)f2bf(u0[2]); afrag[s][3] = (short)f2bf(u0[3]);
      afrag[s][4] = (short)f2bf(u1[0]); afrag[s][5] = (short)f2bf(u1[1]);
      afrag[s][6] = (short)f2bf(u1[2]); afrag[s][7] = (short)f2bf(u1[3]);
    }
  }
  __syncthreads();

  // ---- MFMA over 32 N-tiles (nt = n), store D immediately (low VGPR) ----
  // D lane layout: row b = mt*16 + q*4 + reg, col nd = nt*16 + m  (m89/m91)
  unsigned short* pbase = priT + mt * 8192 + q * 2048 + m;  // + reg*512 + nt*16
#pragma unroll 4
  for (int nt = 0; nt < 32; ++nt) {
    const short8* b0p = (const short8*)&wb[(nt * 16 + m) * 72 + q * 8];
    const short8* b1p = (const short8*)&wb[(nt * 16 + m) * 72 + 32 + q * 8];
    short8 bf0 = *b0p, bf1 = *b1p;
    floatx4 acc = {0.f, 0.f, 0.f, 0.f};
    acc = __builtin_amdgcn_mfma_f32_16x16x32_bf16(afrag[0], bf0, acc, 0, 0, 0);
    acc = __builtin_amdgcn_mfma_f32_16x16x32_bf16(afrag[1], bf1, acc, 0, 0, 0);
    unsigned short* pt = pbase + nt * 16;
    pt[0]    = f2bf(acc[0]);
    pt[512]  = f2bf(acc[1]);
    pt[1024] = f2bf(acc[2]);
    pt[1536] = f2bf(acc[3]);
  }
}

// ---------------------------------------------------------------------------
// Routing pass: per (b,t): logit[n] = <Vc[b,n,:], pri[b,t,n,:]>,
// rc = softmax_n, acc[b,n,d] += rc*pri. Block = (slice=(mod,chunk of 16 t), mt).
// 512 threads = (bl=tid>>5, n=tid&31); wave reads 2KB contiguous per t.
// Writes per-chunk partials (no atomics).
// ---------------------------------------------------------------------------
__global__ __launch_bounds__(512) void pass_kernel(
    const unsigned short* __restrict__ priAll, const float* __restrict__ Vcum,
    float* __restrict__ P) {
  int w = blockIdx.x;
  int slice = w >> 2, mt = w & 3;
  int mod, chunk;
  size_t poff;
  int pbase_f;
  if (slice < 8)       { mod = 0; chunk = slice;      poff = 0;           pbase_f = 0; }
  else if (slice < 40) { mod = 1; chunk = slice - 8;  poff = 4194304ull;  pbase_f = 262144; }
  else if (slice < 56) { mod = 2; chunk = slice - 40; poff = 20971520ull; pbase_f = 1310720; }
  else                 { mod = 3; chunk = slice - 56; poff = 29360128ull; pbase_f = 1835008; }

  int tid = threadIdx.x;
  int n = tid & 31, bl = tid >> 5;
  int b = mt * 16 + bl;

  float Vc[16];
  {
    const floatx4* vp = (const floatx4*)(Vcum + (size_t)mod * 32768 + (size_t)b * 512 + n * 16);
    floatx4 v0 = vp[0], v1 = vp[1], v2 = vp[2], v3 = vp[3];
#pragma unroll
    for (int k = 0; k < 4; ++k) {
      Vc[k] = v0[k]; Vc[4 + k] = v1[k]; Vc[8 + k] = v2[k]; Vc[12 + k] = v3[k];
    }
  }

  float acc[16];
#pragma unroll
  for (int d = 0; d < 16; ++d) acc[d] = 0.f;

  const unsigned short* pb = priAll + poff + (size_t)(chunk * 16) * 32768
                             + mt * 8192 + bl * 512 + n * 16;
  const uint4* q0 = (const uint4*)pb;
  uint4 c0 = q0[0], c1 = q0[1];
  for (int tt = 0; tt < 16; ++tt) {
    uint4 n0, n1;
    if (tt < 15) {
      const uint4* qn = (const uint4*)(pb + (size_t)(tt + 1) * 32768);
      n0 = qn[0];
      n1 = qn[1];
    }
    float p[16];
    {
      unsigned int wds[8] = {c0.x, c0.y, c0.z, c0.w, c1.x, c1.y, c1.z, c1.w};
#pragma unroll
      for (int k = 0; k < 8; ++k) {
        union { unsigned int u; float f; } lo, hi;
        lo.u = wds[k] << 16;
        hi.u = wds[k] & 0xffff0000u;
        p[2 * k] = lo.f;
        p[2 * k + 1] = hi.f;
      }
    }
    float logit = 0.f;
#pragma unroll
    for (int d = 0; d < 16; ++d) logit += p[d] * Vc[d];
    float mx = logit;
#pragma unroll
    for (int o = 16; o >= 1; o >>= 1) mx = fmaxf(mx, __shfl_xor(mx, o, 32));
    float e = __expf(logit - mx);
    float s = e;
#pragma unroll
    for (int o = 16; o >= 1; o >>= 1) s += __shfl_xor(s, o, 32);
    float rc = e / s;
#pragma unroll
    for (int d = 0; d < 16; ++d) acc[d] += rc * p[d];
    c0 = n0;
    c1 = n1;
  }

  floatx4* pp = (floatx4*)(P + pbase_f + (size_t)chunk * 32768 + mt * 8192 + bl * 512 + n * 16);
#pragma unroll
  for (int k = 0; k < 4; ++k) {
    floatx4 v = {acc[4 * k], acc[4 * k + 1], acc[4 * k + 2], acc[4 * k + 3]};
    pp[k] = v;
  }
}

// Reduce partials -> S, then Vcum += tanh(S) (or out = tanh(S) on final pass).
__global__ __launch_bounds__(256) void vred_kernel(
    const float* __restrict__ P, float* __restrict__ Vcum,
    float* __restrict__ out, int final_) {
  int i = blockIdx.x * 256 + threadIdx.x;  // 131072 = [mod][b][n*16+d]
  int local = i & 32767;
  int nc, base;
  if (i < 32768)      { nc = 8;  base = 0; }
  else if (i < 65536) { nc = 32; base = 262144; }
  else if (i < 98304) { nc = 16; base = 1310720; }
  else                { nc = 16; base = 1835008; }
  float s = 0.f;
  for (int c = 0; c < nc; ++c) s += P[base + c * 32768 + local];
  float v = tanhf(s);
  if (final_) out[i] = v;
  else Vcum[i] += v;
}

extern "C" void kernel_launch(void* const* d_in, const int* in_sizes, int n_in,
                              void* d_out, int out_size, void* d_ws, size_t ws_size,
                              hipStream_t stream) {
  const float* x0 = (const float*)d_in[0];
  const float* x1 = (const float*)d_in[1];
  const float* x2 = (const float*)d_in[2];
  const float* x3 = (const float*)d_in[3];
  const float* w0 = (const float*)d_in[4];
  const float* w1 = (const float*)d_in[5];
  const float* w2 = (const float*)d_in[6];
  const float* w3 = (const float*)d_in[7];

  unsigned short* pri = (unsigned short*)d_ws;
  float* P = (float*)((char*)d_ws + PRI_BYTES);
  float* Vcum = P + P_FLOATS;

  pri_kernel<<<1152, 256, 0, stream>>>(x0, x1, x2, x3, w0, w1, w2, w3, pri, Vcum);

  for (int p = 0; p < 4; ++p) {
    pass_kernel<<<288, 512, 0, stream>>>(pri, Vcum, P);
    vred_kernel<<<512, 256, 0, stream>>>(P, Vcum, (float*)d_out, p == 3 ? 1 : 0);
  }
}

// Round 4
// 294.269 us; speedup vs baseline: 1.1484x; 1.0781x over previous
//
#include <hip/hip_runtime.h>

// ---------------------------------------------------------------------------
// CapsuleSequenceToGraph, fp32 in/out. B=64, T={128,512,256,256}, n=32, d=16.
// Identity: b_k[b,t,n] = <Vcum_k[b,n,:], pri[b,t,n,:]>, Vcum_k = sum_{i<k} v_i.
// 4 softmax-weighted-sum passes over pri (Vcum_0 = 0 gives the uniform rc_0).
//
// pri ws layout (bf16), per mod: [t][b][n*16+d]  (row = 512 shorts = 1KB)
// ws (bytes):
//   [0, 75497472)              pri bf16
//   [75497472, +9437184)       P fp32: per-pass partial S rows, [blk][512]
//   [84934656, +524288)        Vcum fp32 [mod][b][n*16+d]
// ---------------------------------------------------------------------------

typedef __attribute__((ext_vector_type(8))) short short8;
typedef __attribute__((ext_vector_type(4))) float floatx4;

#define PRI_BYTES 75497472ull
#define P_FLOATS 2359296ull  // 4608 * 512

static __device__ __forceinline__ unsigned short f2bf(float f) {
  union { float f; unsigned int i; } v;
  v.f = f;
  unsigned int x = v.i;
  return (unsigned short)((x + 0x7fffu + ((x >> 16) & 1u)) >> 16);  // RNE
}

// ---------------------------------------------------------------------------
// pri = x @ W per t, bf16 MFMA 16x16x32. Block = (t, 16-n half): M=64(b) x
// N=256(nd) x K=64(j). 53KB LDS -> 3 blocks/CU. Stores go through a per-wave
// LDS transpose so global writes are coalesced dwordx4 (1KB/inst).
// Blocks 0..255 also zero Vcum.
// ---------------------------------------------------------------------------
__global__ __launch_bounds__(256) void pri_kernel(
    const float* __restrict__ x0, const float* __restrict__ x1,
    const float* __restrict__ x2, const float* __restrict__ x3,
    const float* __restrict__ w0, const float* __restrict__ w1,
    const float* __restrict__ w2, const float* __restrict__ w3,
    unsigned short* __restrict__ priAll, float* __restrict__ Vcum) {
  __shared__ unsigned short wb[256 * 72];   // [nd_local][j] bf16, pitch 72
  __shared__ unsigned short sc[4][16][136]; // per-wave store-transpose scratch

  int blk = blockIdx.x;
  int tid = threadIdx.x;

  if (blk < 256) {  // zero Vcum (pass 0 reads zeros)
    int i = blk * 512 + tid * 2;
    Vcum[i] = 0.f;
    Vcum[i + 1] = 0.f;
  }

  int tpair = blk >> 1, half = blk & 1;
  const float* x;
  const float* W;
  unsigned short* priT;
  int T, t;
  if (tpair < 128)      { x = x0; W = w0; priT = priAll;               T = 128; t = tpair; }
  else if (tpair < 640) { x = x1; W = w1; priT = priAll + 4194304ull;  T = 512; t = tpair - 128; }
  else if (tpair < 896) { x = x2; W = w2; priT = priAll + 20971520ull; T = 256; t = tpair - 640; }
  else                  { x = x3; W = w3; priT = priAll + 29360128ull; T = 256; t = tpair - 896; }
  priT += (size_t)t * 32768;

  // ---- stage W[t, half*16 .. +16, :, :] -> wb[nd_local][j] bf16 ----
  {
    const floatx4* Wf4 = (const floatx4*)(W + (size_t)t * 32768);
    unsigned int* wb32 = (unsigned int*)wb;  // pitch 36 dwords
#pragma unroll
    for (int it = 0; it < 8; ++it) {
      int idx = it * 256 + tid;              // 0..2047
      int nl = idx >> 7, jp = (idx >> 2) & 31, dq = idx & 3;
      int ng = half * 16 + nl;
      floatx4 fa = Wf4[ng * 256 + (2 * jp) * 4 + dq];
      floatx4 fb = Wf4[ng * 256 + (2 * jp + 1) * 4 + dq];
      int rbase = nl * 16 + dq * 4;
#pragma unroll
      for (int k = 0; k < 4; ++k) {
        unsigned int dw = (unsigned int)f2bf(fa[k]) | ((unsigned int)f2bf(fb[k]) << 16);
        wb32[(rbase + k) * 36 + jp] = dw;
      }
    }
  }

  // ---- A fragments: x[b = mt*16+m][k = s*32 + q*8 + i] -> bf16 ----
  int lane = tid & 63, mt = tid >> 6;
  int m = lane & 15, q = lane >> 4;
  short8 afrag[2];
  {
    const float* xrow = x + ((size_t)(mt * 16 + m) * T + t) * 64;
#pragma unroll
    for (int s = 0; s < 2; ++s) {
      const floatx4* xp = (const floatx4*)(xrow + s * 32 + q * 8);
      floatx4 u0 = xp[0], u1 = xp[1];
      afrag[s][0] = (short)f2bf(u0[0]); afrag[s][1] = (short)f2bf(u0[1]);
      afrag[s][2] = (short)f2bf(u0[2]); afrag[s][3] = (short)f2bf(u0[3]);
      afrag[s][4] = (short)f2bf(u1[0]); afrag[s][5] = (short)f2bf(u1[1]);
      afrag[s][6] = (short)f2bf(u1[2]); afrag[s][7] = (short)f2bf(u1[3]);
    }
  }
  __syncthreads();

  // ---- 16 N-tiles; D layout: row b = mt*16+q*4+reg, col nd = nt*16+m ----
  // (so d = m, n = half*16 + nt).  Per 8-tile group: stash bf16 in per-wave
  // LDS scratch, then flush 4 coalesced dwordx4 stores (no block sync needed:
  // sc[mt] is written and read by wave mt only).
  for (int g = 0; g < 2; ++g) {
#pragma unroll
    for (int k = 0; k < 8; ++k) {
      int nt = g * 8 + k;
      const short8* b0p = (const short8*)&wb[(nt * 16 + m) * 72 + q * 8];
      const short8* b1p = (const short8*)&wb[(nt * 16 + m) * 72 + 32 + q * 8];
      short8 bf0 = *b0p, bf1 = *b1p;
      floatx4 acc = {0.f, 0.f, 0.f, 0.f};
      acc = __builtin_amdgcn_mfma_f32_16x16x32_bf16(afrag[0], bf0, acc, 0, 0, 0);
      acc = __builtin_amdgcn_mfma_f32_16x16x32_bf16(afrag[1], bf1, acc, 0, 0, 0);
#pragma unroll
      for (int reg = 0; reg < 4; ++reg)
        sc[mt][q * 4 + reg][k * 16 + m] = f2bf(acc[reg]);
    }
#pragma unroll
    for (int i = 0; i < 4; ++i) {
      int bl = (lane >> 4) + i * 4;
      int sh = (lane & 15) * 8;
      short8 v = *(const short8*)&sc[mt][bl][sh];
      *(short8*)(priT + (size_t)(mt * 16 + bl) * 512 + half * 256 + g * 128 + sh) = v;
    }
  }
}

// ---------------------------------------------------------------------------
// Routing pass: block = (mod, b, chunk of 16 t), 256 thr = 8 groups of 32.
// Group g handles t = chunk*16 + g*2 + {0,1}: loads both rows up front,
// logit = <Vc, p>, softmax over 32 lanes (n), acc += rc*p. Groups reduce via
// LDS; block writes ONE partial S row to P[blk]. 4608 blocks -> ~18/CU.
// ---------------------------------------------------------------------------
__global__ __launch_bounds__(256) void pass_kernel(
    const unsigned short* __restrict__ priAll, const float* __restrict__ Vcum,
    float* __restrict__ P) {
  __shared__ float Sl[8][512];

  int blk = blockIdx.x;
  int mod, b, chunk;
  size_t poff;
  if (blk < 512)       { mod = 0; b = blk >> 3;  chunk = blk & 7;  poff = 0; }
  else if (blk < 2560) { int i = blk - 512;  mod = 1; b = i >> 5; chunk = i & 31; poff = 4194304ull; }
  else if (blk < 3584) { int i = blk - 2560; mod = 2; b = i >> 4; chunk = i & 15; poff = 20971520ull; }
  else                 { int i = blk - 3584; mod = 3; b = i >> 4; chunk = i & 15; poff = 29360128ull; }

  int tid = threadIdx.x;
  int n = tid & 31, g = tid >> 5;

  float Vc[16];
  {
    const floatx4* vp = (const floatx4*)(Vcum + (size_t)mod * 32768 + (size_t)b * 512 + n * 16);
    floatx4 v0 = vp[0], v1 = vp[1], v2 = vp[2], v3 = vp[3];
#pragma unroll
    for (int k = 0; k < 4; ++k) {
      Vc[k] = v0[k]; Vc[4 + k] = v1[k]; Vc[8 + k] = v2[k]; Vc[12 + k] = v3[k];
    }
  }

  // issue all 4 loads (2 t-rows) before any compute
  const unsigned short* pb = priAll + poff + (size_t)(chunk * 16 + g * 2) * 32768
                             + (size_t)b * 512 + n * 16;
  const uint4* q0 = (const uint4*)pb;
  const uint4* q1 = (const uint4*)(pb + 32768);
  uint4 r0a = q0[0], r0b = q0[1];
  uint4 r1a = q1[0], r1b = q1[1];

  float acc[16];
#pragma unroll
  for (int d = 0; d < 16; ++d) acc[d] = 0.f;

#pragma unroll
  for (int tt = 0; tt < 2; ++tt) {
    uint4 ca = tt ? r1a : r0a;
    uint4 cb = tt ? r1b : r0b;
    float p[16];
    {
      unsigned int wds[8] = {ca.x, ca.y, ca.z, ca.w, cb.x, cb.y, cb.z, cb.w};
#pragma unroll
      for (int k = 0; k < 8; ++k) {
        union { unsigned int u; float f; } lo, hi;
        lo.u = wds[k] << 16;
        hi.u = wds[k] & 0xffff0000u;
        p[2 * k] = lo.f;
        p[2 * k + 1] = hi.f;
      }
    }
    float logit = 0.f;
#pragma unroll
    for (int d = 0; d < 16; ++d) logit += p[d] * Vc[d];
    float mx = logit;
#pragma unroll
    for (int o = 16; o >= 1; o >>= 1) mx = fmaxf(mx, __shfl_xor(mx, o, 32));
    float e = __expf(logit - mx);
    float s = e;
#pragma unroll
    for (int o = 16; o >= 1; o >>= 1) s += __shfl_xor(s, o, 32);
    float rc = e / s;
#pragma unroll
    for (int d = 0; d < 16; ++d) acc[d] += rc * p[d];
  }

#pragma unroll
  for (int d = 0; d < 16; ++d) Sl[g][n * 16 + d] = acc[d];
  __syncthreads();

#pragma unroll
  for (int h = 0; h < 2; ++h) {
    int c = tid + h * 256;
    float s = 0.f;
#pragma unroll
    for (int gg = 0; gg < 8; ++gg) s += Sl[gg][c];
    P[(size_t)blk * 512 + c] = s;
  }
}

// Reduce partial rows -> S, then Vcum += tanh(S) (or out = tanh(S), final).
__global__ __launch_bounds__(256) void vred_kernel(
    const float* __restrict__ P, float* __restrict__ Vcum,
    float* __restrict__ out, int final_) {
  int i = blockIdx.x * 256 + threadIdx.x;  // 131072 = [mod][b][nd]
  int local = i & 32767;
  int b = local >> 9, nd = local & 511;
  int nc, row0;
  if (i < 32768)      { nc = 8;  row0 = b * 8; }
  else if (i < 65536) { nc = 32; row0 = 512 + b * 32; }
  else if (i < 98304) { nc = 16; row0 = 2560 + b * 16; }
  else                { nc = 16; row0 = 3584 + b * 16; }
  float s = 0.f;
  for (int c = 0; c < nc; ++c) s += P[(size_t)(row0 + c) * 512 + nd];
  float v = tanhf(s);
  if (final_) out[i] = v;
  else Vcum[i] += v;
}

extern "C" void kernel_launch(void* const* d_in, const int* in_sizes, int n_in,
                              void* d_out, int out_size, void* d_ws, size_t ws_size,
                              hipStream_t stream) {
  const float* x0 = (const float*)d_in[0];
  const float* x1 = (const float*)d_in[1];
  const float* x2 = (const float*)d_in[2];
  const float* x3 = (const float*)d_in[3];
  const float* w0 = (const float*)d_in[4];
  const float* w1 = (const float*)d_in[5];
  const float* w2 = (const float*)d_in[6];
  const float* w3 = (const float*)d_in[7];

  unsigned short* pri = (unsigned short*)d_ws;
  float* P = (float*)((char*)d_ws + PRI_BYTES);
  float* Vcum = P + P_FLOATS;

  pri_kernel<<<2304, 256, 0, stream>>>(x0, x1, x2, x3, w0, w1, w2, w3, pri, Vcum);

  for (int p = 0; p < 4; ++p) {
    pass_kernel<<<4608, 256, 0, stream>>>(pri, Vcum, P);
    vred_kernel<<<512, 256, 0, stream>>>(P, Vcum, (float*)d_out, p == 3 ? 1 : 0);
  }
}